// Round 7
// baseline (1215.140 us; speedup 1.0000x reference)
//
#include <hip/hip_runtime.h>

typedef unsigned int u32;
typedef _Float16 f16;

#define NN 100000
#define NE 3200000
#define NB 256
#define FTD 41
#define DIM 32
#define NBK 782      // ceil(NN/128)
#define SCHUNK 8000  // edges per k_bscatter block; 400*8000 == NE

// ---------------- bucketed CSR build ----------------
__global__ __launch_bounds__(256) void k_bzero(int* __restrict__ bcnt) {
  int g = blockIdx.x * 256 + threadIdx.x;
  if (g < NBK) bcnt[g] = 0;
}

__global__ __launch_bounds__(256) void k_bhist(const int* __restrict__ ei,
                                               int* __restrict__ bcnt) {
  __shared__ int h[NBK];
  int t = threadIdx.x;
  for (int i = t; i < NBK; i += 256) h[i] = 0;
  __syncthreads();
  for (int g = blockIdx.x * 256 + t; g < NE; g += gridDim.x * 256)
    atomicAdd(&h[ei[NE + g] >> 7], 1);
  __syncthreads();
  for (int i = t; i < NBK; i += 256)
    if (h[i]) atomicAdd(&bcnt[i], h[i]);
}

__global__ __launch_bounds__(1024) void k_bscan(const int* __restrict__ bcnt,
                                                int* __restrict__ boff,
                                                int* __restrict__ bcur) {
  __shared__ int sm[1024];
  int t = threadIdx.x;
  int v = (t < NBK) ? bcnt[t] : 0;
  sm[t] = v;
  __syncthreads();
  for (int d = 1; d < 1024; d <<= 1) {
    int x = (t >= d) ? sm[t - d] : 0;
    __syncthreads();
    sm[t] += x;
    __syncthreads();
  }
  if (t < NBK) {
    int excl = sm[t] - v;
    boff[t] = excl;
    bcur[t] = excl;
  }
  if (t == 0) boff[NBK] = NE;
}

// LDS-staged bucket scatter (one global atomic per block,bucket; coalesced flush)
__global__ __launch_bounds__(256) void k_bscatter(const int* __restrict__ ei,
                                                  int* __restrict__ bcur,
                                                  int* __restrict__ ppack) {
  __shared__ int lexcl[NBK];
  __shared__ int lcur[NBK];
  __shared__ int gdelta[NBK];
  __shared__ int lbuf[SCHUNK];
  __shared__ unsigned short lbkt[SCHUNK];
  __shared__ int sm[256];
  int t = threadIdx.x;
  int e0 = blockIdx.x * SCHUNK;
  for (int i = t; i < NBK; i += 256) lexcl[i] = 0;
  __syncthreads();
  for (int i = t; i < SCHUNK; i += 256)
    atomicAdd(&lexcl[((u32)ei[NE + e0 + i]) >> 7], 1);
  __syncthreads();
  int b0 = t * 4;
  int c0 = 0, c1 = 0, c2 = 0, c3 = 0;
  if (b0 < NBK) {
    c0 = lexcl[b0];
    c1 = (b0 + 1 < NBK) ? lexcl[b0 + 1] : 0;
    c2 = (b0 + 2 < NBK) ? lexcl[b0 + 2] : 0;
    c3 = (b0 + 3 < NBK) ? lexcl[b0 + 3] : 0;
  }
  int tot = c0 + c1 + c2 + c3;
  sm[t] = tot;
  __syncthreads();
  for (int d = 1; d < 256; d <<= 1) {
    int x = (t >= d) ? sm[t - d] : 0;
    __syncthreads();
    sm[t] += x;
    __syncthreads();
  }
  int base = sm[t] - tot;
  if (b0 < NBK) {
    int cnts[4] = {c0, c1, c2, c3};
    int e = base;
#pragma unroll
    for (int j = 0; j < 4; j++) {
      int b = b0 + j;
      if (b < NBK) {
        int c = cnts[j];
        lexcl[b] = e;
        lcur[b] = e;
        if (c > 0) gdelta[b] = atomicAdd(&bcur[b], c) - e;
        e += c;
      }
    }
  }
  __syncthreads();
  for (int i = t; i < SCHUNK; i += 256) {
    int s = ei[e0 + i];
    u32 d = (u32)ei[NE + e0 + i];
    int b = d >> 7;
    int p = atomicAdd(&lcur[b], 1);
    lbuf[p] = (int)(((d & 127u) << 20) | (u32)s);
    lbkt[p] = (unsigned short)b;
  }
  __syncthreads();
  for (int i = t; i < SCHUNK; i += 256) {
    int b = lbkt[i];
    ppack[gdelta[b] + i] = lbuf[i];
  }
}

// one block per bucket: per-node counts -> LDS scan -> off[] + final srcs
__global__ __launch_bounds__(256) void k_bfinal(const int* __restrict__ boff,
                                                const int* __restrict__ ppack,
                                                int* __restrict__ off,
                                                int* __restrict__ srcs) {
  __shared__ int ncnt[128];
  __shared__ int nincl[128];
  int b = blockIdx.x, t = threadIdx.x;
  int e0 = boff[b], e1 = boff[b + 1];
  if (t < 128) ncnt[t] = 0;
  __syncthreads();
  for (int i = e0 + t; i < e1; i += 256) atomicAdd(&ncnt[((u32)ppack[i]) >> 20], 1);
  __syncthreads();
  if (t < 128) nincl[t] = ncnt[t];
  __syncthreads();
  for (int d = 1; d < 128; d <<= 1) {
    int x = 0;
    if (t < 128 && t >= d) x = nincl[t - d];
    __syncthreads();
    if (t < 128) nincl[t] += x;
    __syncthreads();
  }
  int node0 = b * 128;
  if (t < 128) {
    int excl = nincl[t] - ncnt[t];
    int node = node0 + t;
    if (node < NN) off[node] = e0 + excl;
    ncnt[t] = excl;
  }
  if (b == 0 && t == 0) off[NN] = NE;
  __syncthreads();
  for (int i = e0 + t; i < e1; i += 256) {
    u32 v = (u32)ppack[i];
    int dl = v >> 20;
    int pos = atomicAdd(&ncnt[dl], 1);
    srcs[e0 + pos] = (int)(v & 0xFFFFF);
  }
}

// ---------------- drug branch ----------------
__global__ __launch_bounds__(256) void k_conv(
    const int* __restrict__ xd, const float* __restrict__ emb,
    const float* __restrict__ convw, const float* __restrict__ convb,
    float* __restrict__ C) {
  __shared__ float e_s[100 * 128];
  __shared__ float w_s[4 * 800];
  __shared__ int xd_s[100];
  int t = threadIdx.x;
  int b = blockIdx.x >> 3;
  int og = (blockIdx.x & 7) << 2;
  if (t < 100) xd_s[t] = xd[b * 100 + t];
  __syncthreads();
  for (int i = t; i < 12800; i += 256)
    e_s[i] = emb[xd_s[i >> 7] * 128 + (i & 127)];
  for (int i = t; i < 3200; i += 256) w_s[i] = convw[og * 800 + i];
  __syncthreads();
  for (int idx = t; idx < 484; idx += 256) {
    int o = idx / 121, h = idx - o * 121;
    const float* wp = &w_s[o * 800];
    const float* ep = &e_s[h];
    float acc = 0.f;
    for (int i = 0; i < 100; i++) {
#pragma unroll
      for (int k = 0; k < 8; k++) acc += ep[i * 128 + k] * wp[i * 8 + k];
    }
    C[b * 3872 + (og + o) * 121 + h] = acc + convb[og + o];
  }
}

__global__ __launch_bounds__(256) void k_fcd(
    const float* __restrict__ C, const float* __restrict__ fcdw,
    const float* __restrict__ fcdb, float* __restrict__ XJ) {
  __shared__ float c_s[3872];
  __shared__ float red[128];
  int t = threadIdx.x, b = blockIdx.x;
  for (int i = t; i < 3872; i += 256) c_s[i] = C[b * 3872 + i];
  __syncthreads();
  int j = t & 127, half = t >> 7;
  float acc = 0.f;
  int k0 = half * 1936;
  for (int k = k0; k < k0 + 1936; k++) acc += c_s[k] * fcdw[k * 128 + j];
  if (half) red[j] = acc;
  __syncthreads();
  if (!half) XJ[b * 256 + j] = acc + red[j] + fcdb[j];
}

// ---------------- protein branch ----------------
// Z0[n] = xt[n] @ g1_w1 (41->32), stored fp16. Also zeros POOL.
__global__ __launch_bounds__(256) void k_z1(
    const float* __restrict__ xt, const float* __restrict__ w1,
    f16* __restrict__ Z, float* __restrict__ pool) {
  __shared__ float xs[256 * FTD];
  __shared__ float w1s[FTD * DIM];
  int t = threadIdx.x;
  int base = blockIdx.x * 256;
  int g = base + t;
  if (g < NB * DIM) pool[g] = 0.f;
  for (int i = t; i < FTD * DIM; i += 256) w1s[i] = w1[i];
  int cnt = min(256, NN - base);
  for (int i = t; i < cnt * FTD; i += 256) xs[i] = xt[base * FTD + i];
  __syncthreads();
  int n = base + t;
  if (n < NN) {
    float acc[DIM];
#pragma unroll
    for (int j = 0; j < DIM; j++) acc[j] = 0.f;
    for (int k = 0; k < FTD; k++) {
      float xk = xs[t * FTD + k];
#pragma unroll
      for (int j = 0; j < DIM; j++) acc[j] += xk * w1s[k * DIM + j];
    }
    f16* zp = &Z[(size_t)n * DIM];
#pragma unroll
    for (int j = 0; j < DIM; j++) zp[j] = (f16)acc[j];
  }
}

// Fused GIN layer: one node per 32-lane group, lane f owns feature f.
// Gather: fixed 32-wide chunks, fully unrolled, clamp+select masking ->
// 32 independent loads in flight (MLP is the whole game here).
template <int HAS_NEXT, int DO_POOL>
__global__ __launch_bounds__(256) void k_gin(
    const int* __restrict__ off, const int* __restrict__ srcs,
    const f16* __restrict__ Zin, const float* __restrict__ b1,
    const float* __restrict__ w2, const float* __restrict__ b2,
    const float* __restrict__ bng, const float* __restrict__ bnb,
    const float* __restrict__ bnrm, const float* __restrict__ bnrv,
    const float* __restrict__ w1n, f16* __restrict__ Zout,
    float* __restrict__ pool, const int* __restrict__ batch) {
  __shared__ float w2s[DIM * DIM];
  __shared__ float w1ns[DIM * DIM];
  int t = threadIdx.x;
  for (int i = t; i < DIM * DIM; i += 256) {
    w2s[i] = w2[i];
    if (HAS_NEXT) w1ns[i] = w1n[i];
  }
  int f = t & 31;
  float b1f = b1[f], b2f = b2[f];
  float sc = bng[f] * rsqrtf(bnrv[f] + 1e-5f);
  float sh = bnb[f] - bnrm[f] * sc;
  __syncthreads();
  int n = blockIdx.x * 8 + (t >> 5);  // grid*8 == NN exactly
  int beg = off[n], end = off[n + 1];
  float a0 = (float)Zin[(size_t)n * DIM + f];
  float a1 = 0.f, a2 = 0.f, a3 = 0.f, a4 = 0.f, a5 = 0.f, a6 = 0.f, a7 = 0.f;
  for (int base = beg; base < end; base += 32) {
    int idx = base + f;
    int sv = (idx < end) ? __builtin_nontemporal_load(&srcs[idx]) : -1;
#pragma unroll
    for (int k = 0; k < 32; k += 8) {
      int s0 = __shfl(sv, k, 32);
      int s1 = __shfl(sv, k + 1, 32);
      int s2 = __shfl(sv, k + 2, 32);
      int s3 = __shfl(sv, k + 3, 32);
      int s4 = __shfl(sv, k + 4, 32);
      int s5 = __shfl(sv, k + 5, 32);
      int s6 = __shfl(sv, k + 6, 32);
      int s7 = __shfl(sv, k + 7, 32);
      float v0 = (float)Zin[(size_t)max(s0, 0) * DIM + f];
      float v1 = (float)Zin[(size_t)max(s1, 0) * DIM + f];
      float v2 = (float)Zin[(size_t)max(s2, 0) * DIM + f];
      float v3 = (float)Zin[(size_t)max(s3, 0) * DIM + f];
      float v4 = (float)Zin[(size_t)max(s4, 0) * DIM + f];
      float v5 = (float)Zin[(size_t)max(s5, 0) * DIM + f];
      float v6 = (float)Zin[(size_t)max(s6, 0) * DIM + f];
      float v7 = (float)Zin[(size_t)max(s7, 0) * DIM + f];
      a0 += (s0 >= 0) ? v0 : 0.f;
      a1 += (s1 >= 0) ? v1 : 0.f;
      a2 += (s2 >= 0) ? v2 : 0.f;
      a3 += (s3 >= 0) ? v3 : 0.f;
      a4 += (s4 >= 0) ? v4 : 0.f;
      a5 += (s5 >= 0) ? v5 : 0.f;
      a6 += (s6 >= 0) ? v6 : 0.f;
      a7 += (s7 >= 0) ? v7 : 0.f;
    }
  }
  float acc = ((a0 + a1) + (a2 + a3)) + ((a4 + a5) + (a6 + a7));
  float hid = fmaxf(acc + b1f, 0.f);
  float o = b2f;
#pragma unroll
  for (int k = 0; k < DIM; k++) o += __shfl(hid, k, 32) * w2s[k * DIM + f];
  float hn = fmaxf(o, 0.f) * sc + sh;
  if (HAS_NEXT) {
    float z = 0.f;
#pragma unroll
    for (int k = 0; k < DIM; k++) z += __shfl(hn, k, 32) * w1ns[k * DIM + f];
    __builtin_nontemporal_store((f16)z, &Zout[(size_t)n * DIM + f]);
  }
  if (DO_POOL) atomicAdd(&pool[batch[n] * DIM + f], hn);
}

__global__ __launch_bounds__(128) void k_fct(
    const float* __restrict__ pool, const float* __restrict__ fctw,
    const float* __restrict__ fctb, float* __restrict__ XJ) {
  __shared__ float p_s[DIM];
  int t = threadIdx.x, b = blockIdx.x;
  if (t < DIM) p_s[t] = pool[b * DIM + t];
  __syncthreads();
  float acc = fctb[t];
  for (int k = 0; k < DIM; k++) acc += p_s[k] * fctw[k * 128 + t];
  XJ[b * 256 + 128 + t] = fmaxf(acc, 0.f);
}

__global__ __launch_bounds__(256) void k_c1(
    const float* __restrict__ XJ, const float* __restrict__ w,
    const float* __restrict__ bias, float* __restrict__ H1) {
  __shared__ float xs[256];
  int t = threadIdx.x, b = blockIdx.y;
  xs[t] = XJ[b * 256 + t];
  __syncthreads();
  int j = blockIdx.x * 256 + t;
  float acc = bias[j];
  for (int k = 0; k < 256; k++) acc += xs[k] * w[k * 1024 + j];
  H1[b * 1024 + j] = fmaxf(acc, 0.f);
}

__global__ __launch_bounds__(256) void k_c2(
    const float* __restrict__ H1, const float* __restrict__ w,
    const float* __restrict__ bias, float* __restrict__ H2) {
  __shared__ float hs[1024];
  int t = threadIdx.x, b = blockIdx.x;
  for (int i = t; i < 1024; i += 256) hs[i] = H1[b * 1024 + i];
  __syncthreads();
  float acc = bias[t];
  for (int k = 0; k < 1024; k++) acc += hs[k] * w[k * 256 + t];
  H2[b * 256 + t] = fmaxf(acc, 0.f);
}

__global__ __launch_bounds__(64) void k_c3(
    const float* __restrict__ H2, const float* __restrict__ w,
    const float* __restrict__ bias, const float* __restrict__ y,
    float* __restrict__ out) {
  int b = blockIdx.x * 64 + threadIdx.x;
  float acc = bias[0];
  for (int k = 0; k < 256; k++) acc += H2[b * 256 + k] * w[k];
  out[b] = acc;
  out[NB + b] = y[b];
}

extern "C" void kernel_launch(void* const* d_in, const int* in_sizes, int n_in,
                              void* d_out, int out_size, void* d_ws,
                              size_t ws_size, hipStream_t stream) {
  const int* xd = (const int*)d_in[0];
  const float* xt = (const float*)d_in[1];
  const int* ei = (const int*)d_in[2];
  const int* batch = (const int*)d_in[3];
  const float* y = (const float*)d_in[4];
  const float* emb = (const float*)d_in[5];
  const float* convw = (const float*)d_in[6];
  const float* convb = (const float*)d_in[7];
  const float* fcdw = (const float*)d_in[8];
  const float* fcdb = (const float*)d_in[9];
  const float* g1w1 = (const float*)d_in[10];
  const float* g1b1 = (const float*)d_in[11];
  const float* g1w2 = (const float*)d_in[12];
  const float* g1b2 = (const float*)d_in[13];
  const float* gw1 = (const float*)d_in[14];
  const float* gb1 = (const float*)d_in[15];
  const float* gw2 = (const float*)d_in[16];
  const float* gb2 = (const float*)d_in[17];
  const float* bng = (const float*)d_in[18];
  const float* bnb = (const float*)d_in[19];
  const float* bnrm = (const float*)d_in[20];
  const float* bnrv = (const float*)d_in[21];
  const float* fctw = (const float*)d_in[22];
  const float* fctb = (const float*)d_in[23];
  const float* c1w = (const float*)d_in[24];
  const float* c1b = (const float*)d_in[25];
  const float* c2w = (const float*)d_in[26];
  const float* c2b = (const float*)d_in[27];
  const float* c3w = (const float*)d_in[28];
  const float* c3b = (const float*)d_in[29];
  float* out = (float*)d_out;

  float* ws = (float*)d_ws;
  f16* Z0 = (f16*)ws;                        // NN*32 f16
  f16* Z1 = Z0 + (size_t)NN * DIM;           // NN*32 f16
  int* srcs = (int*)(Z1 + (size_t)NN * DIM); // NE int
  int* off = srcs + NE;                      // NN+1
  int* bcnt = off + NN + 1;                  // NBK
  int* boff = bcnt + NBK;                    // NBK+1
  int* bcur = boff + NBK + 1;                // NBK
  // union region: ppack (CSR build) aliases drug/classifier temps
  // (safe: stream-ordered; ppack dead after k_bfinal)
  int* ppack = bcur + NBK;                   // NE int
  float* C = (float*)ppack;                  // 256*3872
  float* XJ = C + (size_t)NB * 3872;         // 256*256
  float* H1 = XJ + NB * 256;                 // 256*1024
  float* H2 = H1 + NB * 1024;                // 256*256
  float* POOL = H2 + NB * 256;               // 256*32

  int nblk = (NN + 255) / 256;

  // CSR build (edge list is layer-invariant)
  k_bzero<<<(NBK + 255) / 256, 256, 0, stream>>>(bcnt);
  k_bhist<<<512, 256, 0, stream>>>(ei, bcnt);
  k_bscan<<<1, 1024, 0, stream>>>(bcnt, boff, bcur);
  k_bscatter<<<NE / SCHUNK, 256, 0, stream>>>(ei, bcur, ppack);
  k_bfinal<<<NBK, 256, 0, stream>>>(boff, ppack, off, srcs);

  // drug branch (reuses ppack region — after k_bfinal, stream-ordered)
  k_conv<<<NB * 8, 256, 0, stream>>>(xd, emb, convw, convb, C);
  k_fcd<<<NB, 256, 0, stream>>>(C, fcdw, fcdb, XJ);

  // protein branch
  k_z1<<<nblk, 256, 0, stream>>>(xt, g1w1, Z0, POOL);
  f16* zin = Z0;
  f16* zout = Z1;
  for (int i = 0; i < 5; i++) {
    const float *b1, *w2, *b2;
    if (i == 0) { b1 = g1b1; w2 = g1w2; b2 = g1b2; }
    else {
      b1 = gb1 + (i - 1) * DIM;
      w2 = gw2 + (i - 1) * DIM * DIM;
      b2 = gb2 + (i - 1) * DIM;
    }
    const float* w1n = gw1 + i * DIM * DIM;  // only read when i<4
    if (i < 4)
      k_gin<1, 0><<<NN / 8, 256, 0, stream>>>(
          off, srcs, zin, b1, w2, b2, bng + i * DIM, bnb + i * DIM,
          bnrm + i * DIM, bnrv + i * DIM, w1n, zout, POOL, batch);
    else
      k_gin<0, 1><<<NN / 8, 256, 0, stream>>>(
          off, srcs, zin, b1, w2, b2, bng + i * DIM, bnb + i * DIM,
          bnrm + i * DIM, bnrv + i * DIM, w1n, zout, POOL, batch);
    f16* tmp = zin; zin = zout; zout = tmp;
  }
  k_fct<<<NB, 128, 0, stream>>>(POOL, fctw, fctb, XJ);
  k_c1<<<dim3(4, NB), 256, 0, stream>>>(XJ, c1w, c1b, H1);
  k_c2<<<NB, 256, 0, stream>>>(H1, c2w, c2b, H2);
  k_c3<<<4, 64, 0, stream>>>(H2, c3w, c3b, y, out);
}

// Round 8
// 831.635 us; speedup vs baseline: 1.4611x; 1.4611x over previous
//
#include <hip/hip_runtime.h>

typedef unsigned int u32;
typedef _Float16 f16;

#define NN 100000
#define NE 3200000
#define NB 256
#define FTD 41
#define DIM 32
#define NBK 782      // ceil(NN/128)
#define SCHUNK 8000  // edges per k_bscatter block; 400*8000 == NE

// ---------------- bucketed CSR build ----------------
__global__ __launch_bounds__(256) void k_bzero(int* __restrict__ bcnt) {
  int g = blockIdx.x * 256 + threadIdx.x;
  if (g < NBK) bcnt[g] = 0;
}

__global__ __launch_bounds__(256) void k_bhist(const int* __restrict__ ei,
                                               int* __restrict__ bcnt) {
  __shared__ int h[NBK];
  int t = threadIdx.x;
  for (int i = t; i < NBK; i += 256) h[i] = 0;
  __syncthreads();
  for (int g = blockIdx.x * 256 + t; g < NE; g += gridDim.x * 256)
    atomicAdd(&h[ei[NE + g] >> 7], 1);
  __syncthreads();
  for (int i = t; i < NBK; i += 256)
    if (h[i]) atomicAdd(&bcnt[i], h[i]);
}

__global__ __launch_bounds__(1024) void k_bscan(const int* __restrict__ bcnt,
                                                int* __restrict__ boff,
                                                int* __restrict__ bcur) {
  __shared__ int sm[1024];
  int t = threadIdx.x;
  int v = (t < NBK) ? bcnt[t] : 0;
  sm[t] = v;
  __syncthreads();
  for (int d = 1; d < 1024; d <<= 1) {
    int x = (t >= d) ? sm[t - d] : 0;
    __syncthreads();
    sm[t] += x;
    __syncthreads();
  }
  if (t < NBK) {
    int excl = sm[t] - v;
    boff[t] = excl;
    bcur[t] = excl;
  }
  if (t == 0) boff[NBK] = NE;
}

// LDS-staged bucket scatter (one global atomic per block,bucket; coalesced flush)
__global__ __launch_bounds__(256) void k_bscatter(const int* __restrict__ ei,
                                                  int* __restrict__ bcur,
                                                  int* __restrict__ ppack) {
  __shared__ int lexcl[NBK];
  __shared__ int lcur[NBK];
  __shared__ int gdelta[NBK];
  __shared__ int lbuf[SCHUNK];
  __shared__ unsigned short lbkt[SCHUNK];
  __shared__ int sm[256];
  int t = threadIdx.x;
  int e0 = blockIdx.x * SCHUNK;
  for (int i = t; i < NBK; i += 256) lexcl[i] = 0;
  __syncthreads();
  for (int i = t; i < SCHUNK; i += 256)
    atomicAdd(&lexcl[((u32)ei[NE + e0 + i]) >> 7], 1);
  __syncthreads();
  int b0 = t * 4;
  int c0 = 0, c1 = 0, c2 = 0, c3 = 0;
  if (b0 < NBK) {
    c0 = lexcl[b0];
    c1 = (b0 + 1 < NBK) ? lexcl[b0 + 1] : 0;
    c2 = (b0 + 2 < NBK) ? lexcl[b0 + 2] : 0;
    c3 = (b0 + 3 < NBK) ? lexcl[b0 + 3] : 0;
  }
  int tot = c0 + c1 + c2 + c3;
  sm[t] = tot;
  __syncthreads();
  for (int d = 1; d < 256; d <<= 1) {
    int x = (t >= d) ? sm[t - d] : 0;
    __syncthreads();
    sm[t] += x;
    __syncthreads();
  }
  int base = sm[t] - tot;
  if (b0 < NBK) {
    int cnts[4] = {c0, c1, c2, c3};
    int e = base;
#pragma unroll
    for (int j = 0; j < 4; j++) {
      int b = b0 + j;
      if (b < NBK) {
        int c = cnts[j];
        lexcl[b] = e;
        lcur[b] = e;
        if (c > 0) gdelta[b] = atomicAdd(&bcur[b], c) - e;
        e += c;
      }
    }
  }
  __syncthreads();
  for (int i = t; i < SCHUNK; i += 256) {
    int s = ei[e0 + i];
    u32 d = (u32)ei[NE + e0 + i];
    int b = d >> 7;
    int p = atomicAdd(&lcur[b], 1);
    lbuf[p] = (int)(((d & 127u) << 20) | (u32)s);
    lbkt[p] = (unsigned short)b;
  }
  __syncthreads();
  for (int i = t; i < SCHUNK; i += 256) {
    int b = lbkt[i];
    ppack[gdelta[b] + i] = lbuf[i];
  }
}

// one block per bucket: per-node counts -> LDS scan -> off[] + final srcs
__global__ __launch_bounds__(256) void k_bfinal(const int* __restrict__ boff,
                                                const int* __restrict__ ppack,
                                                int* __restrict__ off,
                                                int* __restrict__ srcs) {
  __shared__ int ncnt[128];
  __shared__ int nincl[128];
  int b = blockIdx.x, t = threadIdx.x;
  int e0 = boff[b], e1 = boff[b + 1];
  if (t < 128) ncnt[t] = 0;
  __syncthreads();
  for (int i = e0 + t; i < e1; i += 256) atomicAdd(&ncnt[((u32)ppack[i]) >> 20], 1);
  __syncthreads();
  if (t < 128) nincl[t] = ncnt[t];
  __syncthreads();
  for (int d = 1; d < 128; d <<= 1) {
    int x = 0;
    if (t < 128 && t >= d) x = nincl[t - d];
    __syncthreads();
    if (t < 128) nincl[t] += x;
    __syncthreads();
  }
  int node0 = b * 128;
  if (t < 128) {
    int excl = nincl[t] - ncnt[t];
    int node = node0 + t;
    if (node < NN) off[node] = e0 + excl;
    ncnt[t] = excl;
  }
  if (b == 0 && t == 0) off[NN] = NE;
  __syncthreads();
  for (int i = e0 + t; i < e1; i += 256) {
    u32 v = (u32)ppack[i];
    int dl = v >> 20;
    int pos = atomicAdd(&ncnt[dl], 1);
    srcs[e0 + pos] = (int)(v & 0xFFFFF);
  }
}

// ---------------- drug branch ----------------
__global__ __launch_bounds__(256) void k_conv(
    const int* __restrict__ xd, const float* __restrict__ emb,
    const float* __restrict__ convw, const float* __restrict__ convb,
    float* __restrict__ C) {
  __shared__ float e_s[100 * 128];
  __shared__ float w_s[4 * 800];
  __shared__ int xd_s[100];
  int t = threadIdx.x;
  int b = blockIdx.x >> 3;
  int og = (blockIdx.x & 7) << 2;
  if (t < 100) xd_s[t] = xd[b * 100 + t];
  __syncthreads();
  for (int i = t; i < 12800; i += 256)
    e_s[i] = emb[xd_s[i >> 7] * 128 + (i & 127)];
  for (int i = t; i < 3200; i += 256) w_s[i] = convw[og * 800 + i];
  __syncthreads();
  for (int idx = t; idx < 484; idx += 256) {
    int o = idx / 121, h = idx - o * 121;
    const float* wp = &w_s[o * 800];
    const float* ep = &e_s[h];
    float acc = 0.f;
    for (int i = 0; i < 100; i++) {
#pragma unroll
      for (int k = 0; k < 8; k++) acc += ep[i * 128 + k] * wp[i * 8 + k];
    }
    C[b * 3872 + (og + o) * 121 + h] = acc + convb[og + o];
  }
}

__global__ __launch_bounds__(256) void k_fcd(
    const float* __restrict__ C, const float* __restrict__ fcdw,
    const float* __restrict__ fcdb, float* __restrict__ XJ) {
  __shared__ float c_s[3872];
  __shared__ float red[128];
  int t = threadIdx.x, b = blockIdx.x;
  for (int i = t; i < 3872; i += 256) c_s[i] = C[b * 3872 + i];
  __syncthreads();
  int j = t & 127, half = t >> 7;
  float acc = 0.f;
  int k0 = half * 1936;
  for (int k = k0; k < k0 + 1936; k++) acc += c_s[k] * fcdw[k * 128 + j];
  if (half) red[j] = acc;
  __syncthreads();
  if (!half) XJ[b * 256 + j] = acc + red[j] + fcdb[j];
}

// ---------------- protein branch ----------------
// Z0[n] = xt[n] @ g1_w1 (41->32), stored fp16. Also zeros POOL.
__global__ __launch_bounds__(256) void k_z1(
    const float* __restrict__ xt, const float* __restrict__ w1,
    f16* __restrict__ Z, float* __restrict__ pool) {
  __shared__ float xs[256 * FTD];
  __shared__ float w1s[FTD * DIM];
  int t = threadIdx.x;
  int base = blockIdx.x * 256;
  int g = base + t;
  if (g < NB * DIM) pool[g] = 0.f;
  for (int i = t; i < FTD * DIM; i += 256) w1s[i] = w1[i];
  int cnt = min(256, NN - base);
  for (int i = t; i < cnt * FTD; i += 256) xs[i] = xt[base * FTD + i];
  __syncthreads();
  int n = base + t;
  if (n < NN) {
    float acc[DIM];
#pragma unroll
    for (int j = 0; j < DIM; j++) acc[j] = 0.f;
    for (int k = 0; k < FTD; k++) {
      float xk = xs[t * FTD + k];
#pragma unroll
      for (int j = 0; j < DIM; j++) acc[j] += xk * w1s[k * DIM + j];
    }
    f16* zp = &Z[n * DIM];
#pragma unroll
    for (int j = 0; j < DIM; j++) zp[j] = (f16)acc[j];
  }
}

// Fused GIN layer: one node per 32-lane group, lane f owns feature f.
// fp16 table; plain (cached) loads; 32-wide unrolled clamp+select gather,
// 8 accumulators; srcs chunk software-pipelined (prefetch next during use).
template <int HAS_NEXT, int DO_POOL>
__global__ __launch_bounds__(256) void k_gin(
    const int* __restrict__ off, const int* __restrict__ srcs,
    const f16* __restrict__ Zin, const float* __restrict__ b1,
    const float* __restrict__ w2, const float* __restrict__ b2,
    const float* __restrict__ bng, const float* __restrict__ bnb,
    const float* __restrict__ bnrm, const float* __restrict__ bnrv,
    const float* __restrict__ w1n, f16* __restrict__ Zout,
    float* __restrict__ pool, const int* __restrict__ batch) {
  __shared__ float w2s[DIM * DIM];
  __shared__ float w1ns[DIM * DIM];
  int t = threadIdx.x;
  for (int i = t; i < DIM * DIM; i += 256) {
    w2s[i] = w2[i];
    if (HAS_NEXT) w1ns[i] = w1n[i];
  }
  int f = t & 31;
  float b1f = b1[f], b2f = b2[f];
  float sc = bng[f] * rsqrtf(bnrv[f] + 1e-5f);
  float sh = bnb[f] - bnrm[f] * sc;
  __syncthreads();
  int n = blockIdx.x * 8 + (t >> 5);  // grid*8 == NN exactly
  int beg = off[n], end = off[n + 1];
  float a0 = (float)Zin[n * DIM + f];
  float a1 = 0.f, a2 = 0.f, a3 = 0.f, a4 = 0.f, a5 = 0.f, a6 = 0.f, a7 = 0.f;
  int sv = (beg + f < end) ? srcs[beg + f] : -1;
  for (int base = beg; base < end; base += 32) {
    int nxt = base + 32 + f;
    int svn = (nxt < end) ? srcs[nxt] : -1;
#pragma unroll
    for (int k = 0; k < 32; k += 8) {
      int s0 = __shfl(sv, k, 32);
      int s1 = __shfl(sv, k + 1, 32);
      int s2 = __shfl(sv, k + 2, 32);
      int s3 = __shfl(sv, k + 3, 32);
      int s4 = __shfl(sv, k + 4, 32);
      int s5 = __shfl(sv, k + 5, 32);
      int s6 = __shfl(sv, k + 6, 32);
      int s7 = __shfl(sv, k + 7, 32);
      float v0 = (float)Zin[max(s0, 0) * DIM + f];
      float v1 = (float)Zin[max(s1, 0) * DIM + f];
      float v2 = (float)Zin[max(s2, 0) * DIM + f];
      float v3 = (float)Zin[max(s3, 0) * DIM + f];
      float v4 = (float)Zin[max(s4, 0) * DIM + f];
      float v5 = (float)Zin[max(s5, 0) * DIM + f];
      float v6 = (float)Zin[max(s6, 0) * DIM + f];
      float v7 = (float)Zin[max(s7, 0) * DIM + f];
      a0 += (s0 >= 0) ? v0 : 0.f;
      a1 += (s1 >= 0) ? v1 : 0.f;
      a2 += (s2 >= 0) ? v2 : 0.f;
      a3 += (s3 >= 0) ? v3 : 0.f;
      a4 += (s4 >= 0) ? v4 : 0.f;
      a5 += (s5 >= 0) ? v5 : 0.f;
      a6 += (s6 >= 0) ? v6 : 0.f;
      a7 += (s7 >= 0) ? v7 : 0.f;
    }
    sv = svn;
  }
  float acc = ((a0 + a1) + (a2 + a3)) + ((a4 + a5) + (a6 + a7));
  float hid = fmaxf(acc + b1f, 0.f);
  float o = b2f;
#pragma unroll
  for (int k = 0; k < DIM; k++) o += __shfl(hid, k, 32) * w2s[k * DIM + f];
  float hn = fmaxf(o, 0.f) * sc + sh;
  if (HAS_NEXT) {
    float z = 0.f;
#pragma unroll
    for (int k = 0; k < DIM; k++) z += __shfl(hn, k, 32) * w1ns[k * DIM + f];
    Zout[n * DIM + f] = (f16)z;
  }
  if (DO_POOL) atomicAdd(&pool[batch[n] * DIM + f], hn);
}

__global__ __launch_bounds__(128) void k_fct(
    const float* __restrict__ pool, const float* __restrict__ fctw,
    const float* __restrict__ fctb, float* __restrict__ XJ) {
  __shared__ float p_s[DIM];
  int t = threadIdx.x, b = blockIdx.x;
  if (t < DIM) p_s[t] = pool[b * DIM + t];
  __syncthreads();
  float acc = fctb[t];
  for (int k = 0; k < DIM; k++) acc += p_s[k] * fctw[k * 128 + t];
  XJ[b * 256 + 128 + t] = fmaxf(acc, 0.f);
}

__global__ __launch_bounds__(256) void k_c1(
    const float* __restrict__ XJ, const float* __restrict__ w,
    const float* __restrict__ bias, float* __restrict__ H1) {
  __shared__ float xs[256];
  int t = threadIdx.x, b = blockIdx.y;
  xs[t] = XJ[b * 256 + t];
  __syncthreads();
  int j = blockIdx.x * 256 + t;
  float acc = bias[j];
  for (int k = 0; k < 256; k++) acc += xs[k] * w[k * 1024 + j];
  H1[b * 1024 + j] = fmaxf(acc, 0.f);
}

__global__ __launch_bounds__(256) void k_c2(
    const float* __restrict__ H1, const float* __restrict__ w,
    const float* __restrict__ bias, float* __restrict__ H2) {
  __shared__ float hs[1024];
  int t = threadIdx.x, b = blockIdx.x;
  for (int i = t; i < 1024; i += 256) hs[i] = H1[b * 1024 + i];
  __syncthreads();
  float acc = bias[t];
  for (int k = 0; k < 1024; k++) acc += hs[k] * w[k * 256 + t];
  H2[b * 256 + t] = fmaxf(acc, 0.f);
}

__global__ __launch_bounds__(64) void k_c3(
    const float* __restrict__ H2, const float* __restrict__ w,
    const float* __restrict__ bias, const float* __restrict__ y,
    float* __restrict__ out) {
  int b = blockIdx.x * 64 + threadIdx.x;
  float acc = bias[0];
  for (int k = 0; k < 256; k++) acc += H2[b * 256 + k] * w[k];
  out[b] = acc;
  out[NB + b] = y[b];
}

extern "C" void kernel_launch(void* const* d_in, const int* in_sizes, int n_in,
                              void* d_out, int out_size, void* d_ws,
                              size_t ws_size, hipStream_t stream) {
  const int* xd = (const int*)d_in[0];
  const float* xt = (const float*)d_in[1];
  const int* ei = (const int*)d_in[2];
  const int* batch = (const int*)d_in[3];
  const float* y = (const float*)d_in[4];
  const float* emb = (const float*)d_in[5];
  const float* convw = (const float*)d_in[6];
  const float* convb = (const float*)d_in[7];
  const float* fcdw = (const float*)d_in[8];
  const float* fcdb = (const float*)d_in[9];
  const float* g1w1 = (const float*)d_in[10];
  const float* g1b1 = (const float*)d_in[11];
  const float* g1w2 = (const float*)d_in[12];
  const float* g1b2 = (const float*)d_in[13];
  const float* gw1 = (const float*)d_in[14];
  const float* gb1 = (const float*)d_in[15];
  const float* gw2 = (const float*)d_in[16];
  const float* gb2 = (const float*)d_in[17];
  const float* bng = (const float*)d_in[18];
  const float* bnb = (const float*)d_in[19];
  const float* bnrm = (const float*)d_in[20];
  const float* bnrv = (const float*)d_in[21];
  const float* fctw = (const float*)d_in[22];
  const float* fctb = (const float*)d_in[23];
  const float* c1w = (const float*)d_in[24];
  const float* c1b = (const float*)d_in[25];
  const float* c2w = (const float*)d_in[26];
  const float* c2b = (const float*)d_in[27];
  const float* c3w = (const float*)d_in[28];
  const float* c3b = (const float*)d_in[29];
  float* out = (float*)d_out;

  float* ws = (float*)d_ws;
  f16* Z0 = (f16*)ws;                        // NN*32 f16
  f16* Z1 = Z0 + (size_t)NN * DIM;           // NN*32 f16
  int* srcs = (int*)(Z1 + (size_t)NN * DIM); // NE int
  int* off = srcs + NE;                      // NN+1
  int* bcnt = off + NN + 1;                  // NBK
  int* boff = bcnt + NBK;                    // NBK+1
  int* bcur = boff + NBK + 1;                // NBK
  // union region: ppack (CSR build) aliases drug/classifier temps
  // (safe: stream-ordered; ppack dead after k_bfinal)
  int* ppack = bcur + NBK;                   // NE int
  float* C = (float*)ppack;                  // 256*3872
  float* XJ = C + (size_t)NB * 3872;         // 256*256
  float* H1 = XJ + NB * 256;                 // 256*1024
  float* H2 = H1 + NB * 1024;                // 256*256
  float* POOL = H2 + NB * 256;               // 256*32

  int nblk = (NN + 255) / 256;

  // CSR build (edge list is layer-invariant)
  k_bzero<<<(NBK + 255) / 256, 256, 0, stream>>>(bcnt);
  k_bhist<<<512, 256, 0, stream>>>(ei, bcnt);
  k_bscan<<<1, 1024, 0, stream>>>(bcnt, boff, bcur);
  k_bscatter<<<NE / SCHUNK, 256, 0, stream>>>(ei, bcur, ppack);
  k_bfinal<<<NBK, 256, 0, stream>>>(boff, ppack, off, srcs);

  // drug branch (reuses ppack region — after k_bfinal, stream-ordered)
  k_conv<<<NB * 8, 256, 0, stream>>>(xd, emb, convw, convb, C);
  k_fcd<<<NB, 256, 0, stream>>>(C, fcdw, fcdb, XJ);

  // protein branch
  k_z1<<<nblk, 256, 0, stream>>>(xt, g1w1, Z0, POOL);
  f16* zin = Z0;
  f16* zout = Z1;
  for (int i = 0; i < 5; i++) {
    const float *b1, *w2, *b2;
    if (i == 0) { b1 = g1b1; w2 = g1w2; b2 = g1b2; }
    else {
      b1 = gb1 + (i - 1) * DIM;
      w2 = gw2 + (i - 1) * DIM * DIM;
      b2 = gb2 + (i - 1) * DIM;
    }
    const float* w1n = gw1 + i * DIM * DIM;  // only read when i<4
    if (i < 4)
      k_gin<1, 0><<<NN / 8, 256, 0, stream>>>(
          off, srcs, zin, b1, w2, b2, bng + i * DIM, bnb + i * DIM,
          bnrm + i * DIM, bnrv + i * DIM, w1n, zout, POOL, batch);
    else
      k_gin<0, 1><<<NN / 8, 256, 0, stream>>>(
          off, srcs, zin, b1, w2, b2, bng + i * DIM, bnb + i * DIM,
          bnrm + i * DIM, bnrv + i * DIM, w1n, zout, POOL, batch);
    f16* tmp = zin; zin = zout; zout = tmp;
  }
  k_fct<<<NB, 128, 0, stream>>>(POOL, fctw, fctb, XJ);
  k_c1<<<dim3(4, NB), 256, 0, stream>>>(XJ, c1w, c1b, H1);
  k_c2<<<NB, 256, 0, stream>>>(H1, c2w, c2b, H2);
  k_c3<<<4, 64, 0, stream>>>(H2, c3w, c3b, y, out);
}